// Round 1
// baseline (780.811 us; speedup 1.0000x reference)
//
#include <hip/hip_runtime.h>
#include <stdint.h>

#define B_ 16
#define A_ 9
#define H_ 128
#define W_ 128
#define HW_ (H_*W_)
#define N_ (HW_*A_)          // 147456 proposals per image
#define PRE_ 2000
#define POST_ 300
#define CAND_CAP 4096

typedef unsigned int u32;
typedef unsigned long long u64;

// ---- workspace layout (bytes) ----
#define OFF_KEYS   0ull
#define OFF_STATE  (OFF_KEYS  + (u64)B_*N_*4)         // 9,437,184
#define OFF_CAND   (OFF_STATE + 256ull)               // per-image {prefix, remaining, count, pad}
#define OFF_SELBOX (OFF_CAND  + (u64)B_*CAND_CAP*8)
#define OFF_LIVE   (OFF_SELBOX+ (u64)B_*PRE_*16)
#define OFF_ALIVE  (OFF_LIVE  + (u64)B_*32*8)
#define OFF_SUPP   (OFF_ALIVE + (u64)B_*32*8)
// total = OFF_SUPP + B*PRE*32*8 = ~17.8 MB

__device__ __forceinline__ u32 mono_key(float f) {
    u32 u = __float_as_uint(f);
    return (u & 0x80000000u) ? ~u : (u | 0x80000000u);
}

// ---------------- stage 1: decode boxes + fg scores + validity mask ----------------
__global__ __launch_bounds__(256) void decode_kernel(
        const float* __restrict__ scores,
        const float* __restrict__ deltas,
        const float* __restrict__ anchors,
        const float* __restrict__ im_info,
        float* __restrict__ outprop,
        u32* __restrict__ keys) {
    int t = blockIdx.x * 256 + threadIdx.x;   // over B*A*HW, pixel fastest (coalesced)
    int p  = t & (HW_ - 1);
    int ba = t >> 14;
    int a = ba % A_;
    int b = ba / A_;

    // softmax fg prob, jax-style max-subtracted: fg = e1/(e0+e1)
    float s0 = scores[((b*2*A_ + a)      << 14) + p];
    float s1 = scores[((b*2*A_ + A_ + a) << 14) + p];
    float m  = fmaxf(s0, s1);
    float e0 = expf(s0 - m);
    float e1 = expf(s1 - m);
    float fg = e1 / (e0 + e1);

    float4 anc = ((const float4*)anchors)[p*A_ + a];
    float w  = anc.z - anc.x + 1.0f;
    float h  = anc.w - anc.y + 1.0f;
    float cx = anc.x + 0.5f*w;
    float cy = anc.y + 0.5f*h;

    const float* dbase = deltas + (u64)(((b*4*A_ + 4*a) << 14) + p);
    float dx = dbase[0];
    float dy = dbase[HW_];
    float dw = dbase[2*HW_];
    float dh = dbase[3*HW_];

    float pcx = dx*w + cx;
    float pcy = dy*h + cy;
    float pw  = expf(dw)*w;
    float ph  = expf(dh)*h;
    float x1 = pcx - 0.5f*pw, y1 = pcy - 0.5f*ph;
    float x2 = pcx + 0.5f*pw, y2 = pcy + 0.5f*ph;

    float wmax = im_info[b*4 + 1] - 1.0f;
    float hmax = im_info[b*4 + 0] - 1.0f;
    x1 = fminf(fmaxf(x1, 0.0f), wmax);
    y1 = fminf(fmaxf(y1, 0.0f), hmax);
    x2 = fminf(fmaxf(x2, 0.0f), wmax);
    y2 = fminf(fmaxf(y2, 0.0f), hmax);

    int n = p*A_ + a;
    ((float4*)outprop)[(u64)b*N_ + n] = make_float4(x1, y1, x2, y2);

    float bw = x2 - x1 + 1.0f;
    float bh = y2 - y1 + 1.0f;
    bool valid = (bw >= 16.0f*im_info[b*4 + 3]) && (bh >= 16.0f*im_info[b*4 + 2]);
    float sc = valid ? fg : -__builtin_inff();
    keys[(u64)b*N_ + n] = mono_key(sc);
}

// ---------------- stage 2: radix-select 2000th largest key per image ----------------
__global__ __launch_bounds__(1024) void radix_pass_kernel(
        const u32* __restrict__ keys, u32* __restrict__ state, int shift) {
    int b = blockIdx.x, tid = threadIdx.x;
    __shared__ u32 hist[256];
    for (int i = tid; i < 256; i += 1024) hist[i] = 0;
    __syncthreads();
    u32 prefix = 0, remaining = PRE_;
    if (shift != 24) { prefix = state[b*4 + 0]; remaining = state[b*4 + 1]; }
    const u32* kb = keys + (u64)b*N_;
    for (int n = tid; n < N_; n += 1024) {
        u32 k = kb[n];
        if (shift == 24 || (k >> (shift + 8)) == prefix)
            atomicAdd(&hist[(k >> shift) & 255u], 1u);
    }
    __syncthreads();
    if (tid == 0) {
        for (int bin = 255; bin >= 0; --bin) {
            u32 c = hist[bin];
            if (remaining > c) remaining -= c;
            else { prefix = (prefix << 8) | (u32)bin; break; }
        }
        state[b*4 + 0] = prefix;     // after shift==0 pass: full 32-bit threshold key T
        state[b*4 + 1] = remaining;  // # to take among ==T (smallest indices first)
        state[b*4 + 2] = 0;          // collect counter
    }
}

__global__ __launch_bounds__(1024) void collect_kernel(
        const u32* __restrict__ keys, u32* __restrict__ state, u64* __restrict__ cand) {
    int b = blockIdx.x, tid = threadIdx.x;
    u32 T = state[b*4 + 0];
    const u32* kb = keys + (u64)b*N_;
    u64* cb = cand + (u64)b*CAND_CAP;
    for (int n = tid; n < N_; n += 1024) {
        u32 k = kb[n];
        if (k >= T) {
            u32 pos = atomicAdd(&state[b*4 + 2], 1u);
            // key desc, index asc  ==  packed (key, ~n) desc
            if (pos < CAND_CAP) cb[pos] = ((u64)k << 32) | (u32)(~n);
        }
    }
}

// ---------------- stage 3: sort candidates, gather top-2000 boxes ----------------
__global__ __launch_bounds__(1024) void sort_kernel(
        const u64* __restrict__ cand, const u32* __restrict__ state,
        const float* __restrict__ outprop,
        float4* __restrict__ selbox, u64* __restrict__ livew) {
    int b = blockIdx.x, tid = threadIdx.x;
    __shared__ u64 s[CAND_CAP];
    __shared__ unsigned char lv[2048];
    u32 cnt = state[b*4 + 2];
    if (cnt > CAND_CAP) cnt = CAND_CAP;
    const u64* cb = cand + (u64)b*CAND_CAP;
    for (int i = tid; i < CAND_CAP; i += 1024) s[i] = (i < (int)cnt) ? cb[i] : 0ull;
    for (int i = tid; i < 2048; i += 1024) lv[i] = 0;

    for (u32 k = 2; k <= CAND_CAP; k <<= 1) {
        for (u32 j = k >> 1; j > 0; j >>= 1) {
            __syncthreads();
            for (u32 e = tid; e < CAND_CAP; e += 1024) {
                u32 ixj = e ^ j;
                if (ixj > e) {
                    u64 x = s[e], y = s[ixj];
                    bool descend = ((e & k) == 0);
                    if (descend ? (x < y) : (x > y)) { s[e] = y; s[ixj] = x; }
                }
            }
        }
    }
    __syncthreads();
    for (int r = tid; r < PRE_; r += 1024) {
        u64 e = s[r];
        u32 key = (u32)(e >> 32);
        u32 n = ~(u32)e;
        float4 box = make_float4(0.f, 0.f, 0.f, 0.f);
        if (e != 0ull) box = ((const float4*)outprop)[(u64)b*N_ + n];
        selbox[(u64)b*PRE_ + r] = box;
        lv[r] = (key >= 0x80000000u) ? 1 : 0;   // finite score (valid fg prob >= 0)
    }
    __syncthreads();
    for (int w = tid; w < 32; w += 1024) {
        u64 word = 0;
        for (int bit = 0; bit < 64; ++bit) {
            int r = w*64 + bit;
            if (r < PRE_ && lv[r]) word |= (1ull << bit);
        }
        livew[b*32 + w] = word;
    }
}

// ---------------- stage 4: 2000x2000 IoU suppression bitmask ----------------
__global__ __launch_bounds__(256) void iou_kernel(
        const float4* __restrict__ selbox, const float* __restrict__ thrp,
        u64* __restrict__ supp) {
    int bi = blockIdx.x;             // B * 250 blocks, 8 rows each
    int b = bi / 250;
    int rbase = (bi % 250) * 8;
    int tid = threadIdx.x;
    __shared__ float4 box[PRE_];
    for (int i = tid; i < PRE_; i += 256) box[i] = selbox[(u64)b*PRE_ + i];
    __syncthreads();
    float thresh = thrp[0];
    int wv = tid >> 6, lane = tid & 63;

    float4 p[8]; float ai[8];
    #pragma unroll
    for (int r = 0; r < 8; ++r) {
        p[r]  = box[rbase + r];
        ai[r] = (p[r].z - p[r].x + 1.f) * (p[r].w - p[r].y + 1.f);
    }
    for (int c = 0; c < 8; ++c) {
        int j = c*256 + tid;
        bool inb = (j < PRE_);
        float4 q = box[inb ? j : 0];
        float aj = (q.z - q.x + 1.f) * (q.w - q.y + 1.f);
        #pragma unroll
        for (int r = 0; r < 8; ++r) {
            float iw = fminf(p[r].z, q.z) - fmaxf(p[r].x, q.x) + 1.f;
            float ih = fminf(p[r].w, q.w) - fmaxf(p[r].y, q.y) + 1.f;
            iw = fmaxf(iw, 0.f); ih = fmaxf(ih, 0.f);
            float inter = iw * ih;
            bool pred = inb && ((inter / (ai[r] + aj - inter)) > thresh);
            u64 ball = __ballot(pred);
            if (lane == 0)
                supp[((u64)(b*PRE_ + rbase + r))*32 + (c*4 + wv)] = ball;
        }
    }
}

// ---------------- stage 5: sequential greedy scan over bitmask (1 wave / image) ----------------
__global__ __launch_bounds__(64) void nms_scan_kernel(
        const u64* __restrict__ supp, const u64* __restrict__ livew,
        u64* __restrict__ alivew) {
    int b = blockIdx.x, lane = threadIdx.x;
    u64 alive = (lane < 32) ? livew[b*32 + lane] : 0ull;
    const u64* rows = supp + (u64)b*PRE_*32;
    for (int i0 = 0; i0 < PRE_; i0 += 8) {
        u64 r[8];
        #pragma unroll
        for (int k = 0; k < 8; ++k)
            r[k] = (lane < 32) ? rows[(u64)(i0 + k)*32 + lane] : 0ull;
        #pragma unroll
        for (int k = 0; k < 8; ++k) {
            int i = i0 + k;
            int wi = i >> 6, bit = i & 63;
            // 64-bit shfl via two 32-bit shfls (broadcast word wi of alive bitmap)
            u32 lo = (u32)__shfl((int)(u32)(alive & 0xFFFFFFFFull), wi);
            u32 hi = (u32)__shfl((int)(u32)(alive >> 32), wi);
            u64 aw = ((u64)hi << 32) | lo;
            if ((aw >> bit) & 1ull) {
                u64 m;
                if (lane > wi)       m = ~0ull;
                else if (lane == wi) m = (bit == 63) ? 0ull : (~0ull << (bit + 1));
                else                 m = 0ull;
                alive &= ~(r[k] & m);
            }
        }
    }
    if (lane < 32) alivew[b*32 + lane] = alive;
}

// ---------------- stage 6: compact kept boxes into (B, 300, 5) ----------------
__global__ __launch_bounds__(64) void output_kernel(
        const u64* __restrict__ alivew, const float4* __restrict__ selbox,
        float* __restrict__ out0) {
    int b = blockIdx.x, lane = threadIdx.x;
    u64 w = (lane < 32) ? alivew[b*32 + lane] : 0ull;
    int pc = (int)__builtin_popcountll(w);
    int x = pc;
    for (int off = 1; off < 64; off <<= 1) {
        int y = __shfl_up(x, off);
        if (lane >= off) x += y;
    }
    int base = x - pc;   // exclusive prefix of kept counts over words

    __shared__ int kept[POST_];
    for (int r = lane; r < POST_; r += 64) kept[r] = -1;
    __syncthreads();
    int cnt = 0;
    u64 tmp = w;
    while (tmp) {
        int bitpos = (int)__builtin_ctzll(tmp);
        tmp &= tmp - 1;
        int rank = base + cnt; cnt++;
        if (rank < POST_) kept[rank] = lane*64 + bitpos;
    }
    __syncthreads();
    for (int r = lane; r < POST_; r += 64) {
        int i = kept[r];
        float o1 = 0.f, o2 = 0.f, o3 = 0.f, o4 = 0.f;
        if (i >= 0) {
            float4 bx = selbox[(u64)b*PRE_ + i];
            o1 = bx.x; o2 = bx.y; o3 = bx.z; o4 = bx.w;
        }
        float* rowp = out0 + (u64)(b*POST_ + r)*5;
        rowp[0] = (float)b;  // batch idx written for ALL rows (matches reference)
        rowp[1] = o1; rowp[2] = o2; rowp[3] = o3; rowp[4] = o4;
    }
}

extern "C" void kernel_launch(void* const* d_in, const int* in_sizes, int n_in,
                              void* d_out, int out_size, void* d_ws, size_t ws_size,
                              hipStream_t stream) {
    const float* scores  = (const float*)d_in[0];
    const float* deltas  = (const float*)d_in[1];
    const float* anchors = (const float*)d_in[2];
    const float* im_info = (const float*)d_in[3];
    const float* thrp    = (const float*)d_in[7];   // nms_thresh (device scalar)

    float* out0    = (float*)d_out;                 // (16, 300, 5)
    float* outprop = out0 + (u64)B_*POST_*5;        // (16, 147456, 4)

    char* ws = (char*)d_ws;
    u32*    keys   = (u32*)   (ws + OFF_KEYS);
    u32*    state  = (u32*)   (ws + OFF_STATE);
    u64*    cand   = (u64*)   (ws + OFF_CAND);
    float4* selbox = (float4*)(ws + OFF_SELBOX);
    u64*    livew  = (u64*)   (ws + OFF_LIVE);
    u64*    alivew = (u64*)   (ws + OFF_ALIVE);
    u64*    supp   = (u64*)   (ws + OFF_SUPP);

    decode_kernel<<<(B_*A_*HW_)/256, 256, 0, stream>>>(scores, deltas, anchors, im_info, outprop, keys);
    radix_pass_kernel<<<B_, 1024, 0, stream>>>(keys, state, 24);
    radix_pass_kernel<<<B_, 1024, 0, stream>>>(keys, state, 16);
    radix_pass_kernel<<<B_, 1024, 0, stream>>>(keys, state, 8);
    radix_pass_kernel<<<B_, 1024, 0, stream>>>(keys, state, 0);
    collect_kernel<<<B_, 1024, 0, stream>>>(keys, state, cand);
    sort_kernel<<<B_, 1024, 0, stream>>>(cand, state, outprop, selbox, livew);
    iou_kernel<<<B_*250, 256, 0, stream>>>(selbox, thrp, supp);
    nms_scan_kernel<<<B_, 64, 0, stream>>>(supp, livew, alivew);
    output_kernel<<<B_, 64, 0, stream>>>(alivew, selbox, out0);
}

// Round 2
// 640.369 us; speedup vs baseline: 1.2193x; 1.2193x over previous
//
#include <hip/hip_runtime.h>
#include <stdint.h>

#define B_ 16
#define A_ 9
#define H_ 128
#define W_ 128
#define HW_ (H_*W_)
#define N_ (HW_*A_)          // 147456 proposals per image
#define PRE_ 2000
#define POST_ 300
#define CAND_CAP 4096
#define TR_ 128              // NMS tile rows
#define NT_ ((PRE_ + TR_ - 1)/TR_)   // 16

typedef unsigned int u32;
typedef unsigned long long u64;

// ---- workspace layout (bytes) ----
// [state | hist0..3] zeroed by one hipMemsetAsync at launch start.
#define OFF_STATE  0ull                               // B * 8 u32 = 512
#define OFF_HIST   1024ull                            // 4 passes * B*256 u32 = 65536
#define OFF_KEYS   (OFF_HIST + 65536ull)
#define OFF_CAND   (OFF_KEYS + (u64)B_*N_*4)
#define OFF_SELBOX (OFF_CAND + (u64)B_*CAND_CAP*8)
#define OFF_LIVE   (OFF_SELBOX + (u64)B_*PRE_*16)
// end = OFF_LIVE + B*32*8  (~10.5 MB total)

__device__ __forceinline__ u32 mono_key(float f) {
    u32 u = __float_as_uint(f);
    return (u & 0x80000000u) ? ~u : (u | 0x80000000u);
}

// ---------------- stage 1: decode boxes + fg scores + keys + pass-1 histogram ----------------
// keys stored in (b, a, p) layout -> fully coalesced writes; collect recovers n = p*9+a.
__global__ __launch_bounds__(256) void decode_kernel(
        const float* __restrict__ scores,
        const float* __restrict__ deltas,
        const float* __restrict__ anchors,
        const float* __restrict__ im_info,
        float* __restrict__ outprop,
        u32* __restrict__ keys,
        u32* __restrict__ hist0) {
    __shared__ float4 sbase[A_];
    __shared__ u32 h[256];
    int tid = threadIdx.x;
    if (tid < A_) sbase[tid] = ((const float4*)anchors)[tid];  // anchors[p=0] == base anchors
    h[tid] = 0;
    __syncthreads();

    int t = blockIdx.x * 256 + tid;   // over B*A*HW, pixel fastest; one (b,a) per block
    int p  = t & (HW_ - 1);
    int ba = t >> 14;
    int a = ba % A_;
    int b = ba / A_;

    // softmax fg prob
    float s0 = scores[((b*2*A_ + a)      << 14) + p];
    float s1 = scores[((b*2*A_ + A_ + a) << 14) + p];
    float m  = fmaxf(s0, s1);
    float e0 = expf(s0 - m);
    float e1 = expf(s1 - m);
    float fg = e1 / (e0 + e1);

    // analytic anchor: base[a] + (sx,sy,sx,sy), exact fp32
    float4 base = sbase[a];
    int ix = p & (W_-1), iy = p >> 7;
    float sx = (float)(ix * 16), sy = (float)(iy * 16);
    float ax1 = base.x + sx, ay1 = base.y + sy, ax2 = base.z + sx, ay2 = base.w + sy;

    float w  = ax2 - ax1 + 1.0f;
    float h_ = ay2 - ay1 + 1.0f;
    float cx = ax1 + 0.5f*w;
    float cy = ay1 + 0.5f*h_;

    const float* dbase = deltas + (u64)(((b*4*A_ + 4*a) << 14) + p);
    float dx = dbase[0];
    float dy = dbase[HW_];
    float dw = dbase[2*HW_];
    float dh = dbase[3*HW_];

    float pcx = dx*w  + cx;
    float pcy = dy*h_ + cy;
    float pw  = expf(dw)*w;
    float ph  = expf(dh)*h_;
    float x1 = pcx - 0.5f*pw, y1 = pcy - 0.5f*ph;
    float x2 = pcx + 0.5f*pw, y2 = pcy + 0.5f*ph;

    float wmax = im_info[b*4 + 1] - 1.0f;
    float hmax = im_info[b*4 + 0] - 1.0f;
    x1 = fminf(fmaxf(x1, 0.0f), wmax);
    y1 = fminf(fmaxf(y1, 0.0f), hmax);
    x2 = fminf(fmaxf(x2, 0.0f), wmax);
    y2 = fminf(fmaxf(y2, 0.0f), hmax);

    int n = p*A_ + a;
    ((float4*)outprop)[(u64)b*N_ + n] = make_float4(x1, y1, x2, y2);

    float bw = x2 - x1 + 1.0f;
    float bh = y2 - y1 + 1.0f;
    bool valid = (bw >= 16.0f*im_info[b*4 + 3]) && (bh >= 16.0f*im_info[b*4 + 2]);
    float sc = valid ? fg : -__builtin_inff();
    u32 k = mono_key(sc);
    keys[((u64)(b*A_ + a) << 14) + p] = k;       // coalesced (a,p) layout
    atomicAdd(&h[k >> 24], 1u);
    __syncthreads();
    if (h[tid]) atomicAdd(&hist0[b*256 + tid], h[tid]);
}

// ---------------- stage 2a: histogram pass (shifts 16, 8, 0), prefix-filtered ----------------
__global__ __launch_bounds__(1024) void hist_kernel(
        const u32* __restrict__ keys, const u32* __restrict__ state,
        u32* __restrict__ hist, int shift) {
    int b = blockIdx.x >> 4;
    int slice = blockIdx.x & 15;
    if (state[b*8 + 3]) return;                   // already done
    __shared__ u32 h[256];
    int tid = threadIdx.x;
    for (int i = tid; i < 256; i += 1024) h[i] = 0;
    __syncthreads();
    u32 prefix = state[b*8 + 0];
    const u32* kb = keys + (u64)b*N_ + slice*(N_/16);
    for (int n = tid; n < N_/16; n += 1024) {
        u32 k = kb[n];
        if ((k >> (shift + 8)) == prefix) atomicAdd(&h[(k >> shift) & 255u], 1u);
    }
    __syncthreads();
    for (int i = tid; i < 256; i += 1024)
        if (h[i]) atomicAdd(&hist[b*256 + i], h[i]);
}

// ---------------- stage 2b: pick bin (parallel suffix-scan over 256 bins) ----------------
__global__ __launch_bounds__(64) void select_kernel(
        const u32* __restrict__ hist, u32* __restrict__ state, int shift) {
    int b = blockIdx.x, lane = threadIdx.x;
    if (state[b*8 + 3]) return;
    u32 rem0   = (shift == 24) ? (u32)PRE_ : state[b*8 + 1];
    u32 prefix = (shift == 24) ? 0u        : state[b*8 + 0];
    uint4 hv = ((const uint4*)(hist + b*256))[lane];   // bins 4l..4l+3
    u32 psum = hv.x + hv.y + hv.z + hv.w;
    u32 s = psum;                                      // inclusive suffix sum over lanes
    #pragma unroll
    for (int off = 1; off < 64; off <<= 1) {
        u32 o = (u32)__shfl_down((int)s, off);
        if (lane + off < 64) s += o;
    }
    u32 S_next = (u32)__shfl_down((int)s, 1);
    if (lane == 63) S_next = 0;
    u32 above[4], cnt[4];
    above[3] = S_next;             cnt[3] = hv.w;
    above[2] = S_next + hv.w;      cnt[2] = hv.z;
    above[1] = above[2] + hv.z;    cnt[1] = hv.y;
    above[0] = above[1] + hv.y;    cnt[0] = hv.x;
    #pragma unroll
    for (int j = 3; j >= 0; --j) {
        if (above[j] < rem0 && above[j] + cnt[j] >= rem0) {
            u32 bin = (u32)(4*lane + j);
            u32 newpref = (prefix << 8) | bin;
            u32 rem = rem0 - above[j];                 // still needed within chosen bin
            u32 candTotal = ((u32)PRE_ - rem) + cnt[j];
            if (candTotal <= (u32)CAND_CAP || shift == 0) {
                state[b*8 + 4] = newpref << shift;     // threshold key T
                state[b*8 + 3] = 1;                    // done
            } else {
                state[b*8 + 0] = newpref;
                state[b*8 + 1] = rem;
            }
        }
    }
}

// ---------------- stage 3: collect all keys >= T ----------------
__global__ __launch_bounds__(1024) void collect_kernel(
        const u32* __restrict__ keys, u32* __restrict__ state, u64* __restrict__ cand) {
    int b = blockIdx.x >> 4;
    int slice = blockIdx.x & 15;
    u32 T = state[b*8 + 4];
    const u32* kb = keys + (u64)b*N_ + slice*(N_/16);
    u64* cb = cand + (u64)b*CAND_CAP;
    int tid = threadIdx.x;
    for (int i = tid; i < N_/16; i += 1024) {
        u32 k = kb[i];
        if (k >= T) {
            u32 pos = atomicAdd(&state[b*8 + 2], 1u);
            int idx = slice*(N_/16) + i;               // (a,p) storage index
            u32 n = (u32)((idx & (HW_-1))*A_ + (idx >> 14));  // n = p*9 + a
            if (pos < CAND_CAP) cb[pos] = ((u64)k << 32) | (u32)(~n);  // key desc, index asc
        }
    }
}

// ---------------- stage 4: bitonic sort candidates, gather top-2000 boxes ----------------
__global__ __launch_bounds__(1024) void sort_kernel(
        const u64* __restrict__ cand, const u32* __restrict__ state,
        const float* __restrict__ outprop,
        float4* __restrict__ selbox, u64* __restrict__ livew) {
    int b = blockIdx.x, tid = threadIdx.x;
    __shared__ u64 s[CAND_CAP];
    __shared__ unsigned char lv[2048];
    u32 cnt = state[b*8 + 2];
    if (cnt > CAND_CAP) cnt = CAND_CAP;
    const u64* cb = cand + (u64)b*CAND_CAP;
    for (int i = tid; i < CAND_CAP; i += 1024) s[i] = (i < (int)cnt) ? cb[i] : 0ull;
    for (int i = tid; i < 2048; i += 1024) lv[i] = 0;

    for (u32 k = 2; k <= CAND_CAP; k <<= 1) {
        for (u32 j = k >> 1; j > 0; j >>= 1) {
            __syncthreads();
            for (u32 e = tid; e < CAND_CAP; e += 1024) {
                u32 ixj = e ^ j;
                if (ixj > e) {
                    u64 x = s[e], y = s[ixj];
                    bool descend = ((e & k) == 0);
                    if (descend ? (x < y) : (x > y)) { s[e] = y; s[ixj] = x; }
                }
            }
        }
    }
    __syncthreads();
    for (int r = tid; r < PRE_; r += 1024) {
        u64 e = s[r];
        u32 key = (u32)(e >> 32);
        u32 n = ~(u32)e;
        float4 box = make_float4(0.f, 0.f, 0.f, 0.f);
        if (e != 0ull) box = ((const float4*)outprop)[(u64)b*N_ + n];
        selbox[(u64)b*PRE_ + r] = box;
        lv[r] = (key >= 0x80000000u) ? 1 : 0;   // finite (valid) score
    }
    __syncthreads();
    for (int w = tid; w < 32; w += 1024) {
        u64 word = 0;
        for (int bit = 0; bit < 64; ++bit) {
            int r = w*64 + bit;
            if (r < PRE_ && lv[r]) word |= (1ull << bit);
        }
        livew[b*32 + w] = word;
    }
}

// ---------------- stage 5: fused NMS (producer waves build IoU bit-tiles in LDS,
//                  wave 0 scans sequentially with early exit at 300 kept) + output ----------------
__global__ __launch_bounds__(1024) void nms_fused_kernel(
        const float4* __restrict__ selbox, const u64* __restrict__ livew,
        const float* __restrict__ thrp, float* __restrict__ out0) {
    int b = blockIdx.x;
    int tid = threadIdx.x;
    int wave = tid >> 6, lane = tid & 63;

    __shared__ float4 sbox[PRE_];        // 32000 B
    __shared__ float  sarea[PRE_];       //  8000 B
    __shared__ u64 tile[2][TR_][32];     // 65536 B
    __shared__ u64 alive_s[32];
    __shared__ int s_stop;
    __shared__ int kept_s[POST_];

    for (int i = tid; i < PRE_; i += 1024) {
        float4 p = selbox[(u64)b*PRE_ + i];
        sbox[i] = p;
        sarea[i] = (p.z - p.x + 1.f)*(p.w - p.y + 1.f);
    }
    if (tid == 0) s_stop = 0;
    __syncthreads();
    float thresh = thrp[0];

    u64 alive = (wave == 0 && lane < 32) ? livew[b*32 + lane] : 0ull;

    // producer: compute suppression bit-tile t into buffer buf using waves [wfirst, 16)
    auto produce = [&](int t, int buf, int wfirst) {
        int r0 = t * TR_;
        int nrows = PRE_ - r0; if (nrows > TR_) nrows = TR_;
        if (nrows <= 0) return;
        int npairs = nrows * 32;
        int wcount = 16 - wfirst;
        for (int pidx = wave - wfirst; pidx < npairs; pidx += wcount) {
            int lr = pidx >> 5;
            int w  = pidx & 31;
            float4 p = sbox[r0 + lr];
            float ai = sarea[r0 + lr];
            int j = w*64 + lane;
            int jj = (j < PRE_) ? j : 0;
            float4 q = sbox[jj];
            float aj = sarea[jj];
            float iw = fminf(p.z, q.z) - fmaxf(p.x, q.x) + 1.f;
            float ih = fminf(p.w, q.w) - fmaxf(p.y, q.y) + 1.f;
            iw = fmaxf(iw, 0.f); ih = fmaxf(ih, 0.f);
            float inter = iw * ih;
            bool pred = (j < PRE_) && ((inter / (ai + aj - inter)) > thresh);
            u64 ball = __ballot(pred);
            if (lane == 0) tile[buf][lr][w] = ball;
        }
    };

    produce(0, 0, 0);           // all 16 waves build tile 0
    __syncthreads();

    int kept = 0;
    for (int t = 0; t < NT_; ++t) {
        if (wave == 0) {
            int r0 = t * TR_;
            int nrows = PRE_ - r0; if (nrows > TR_) nrows = TR_;
            bool stopped = false;
            for (int li0 = 0; li0 < nrows && !stopped; li0 += 8) {
                int nk = nrows - li0; if (nk > 8) nk = 8;
                u64 rr[8];
                #pragma unroll
                for (int k = 0; k < 8; ++k)
                    rr[k] = (lane < 32 && k < nk) ? tile[t & 1][li0 + k][lane] : 0ull;
                for (int k = 0; k < nk; ++k) {
                    int i = r0 + li0 + k;
                    int wi = i >> 6, bit = i & 63;
                    u32 lo = (u32)__shfl((int)(u32)(alive & 0xFFFFFFFFull), wi);
                    u32 hi = (u32)__shfl((int)(u32)(alive >> 32), wi);
                    u64 aw = ((u64)hi << 32) | lo;
                    if ((aw >> bit) & 1ull) {
                        kept++;
                        if (kept >= POST_) {     // 300th kept: later rows only affect ranks>300
                            if (lane == 0) s_stop = 1;
                            stopped = true;
                            break;
                        }
                        u64 m;
                        if (lane > wi)       m = ~0ull;
                        else if (lane == wi) m = (bit == 63) ? 0ull : (~0ull << (bit + 1));
                        else                 m = 0ull;
                        alive &= ~(rr[k] & m);
                    }
                }
            }
        } else {
            produce(t + 1, (t + 1) & 1, 1);      // waves 1..15 build next tile
        }
        __syncthreads();
        int st = s_stop;
        __syncthreads();                          // no one overwrites s_stop before all read
        if (st) break;
    }

    if (wave == 0 && lane < 32) alive_s[lane] = alive;
    for (int r = tid; r < POST_; r += 1024) kept_s[r] = -1;
    __syncthreads();

    if (wave == 0) {    // compaction: rank -> selected index
        u64 w = (lane < 32) ? alive_s[lane] : 0ull;
        int pc = (int)__builtin_popcountll(w);
        int x = pc;
        for (int off = 1; off < 64; off <<= 1) {
            int y = __shfl_up(x, off);
            if (lane >= off) x += y;
        }
        int base = x - pc;
        int c = 0;
        u64 tmp = w;
        while (tmp) {
            int bitpos = (int)__builtin_ctzll(tmp);
            tmp &= tmp - 1;
            int rank = base + c; c++;
            if (rank < POST_) kept_s[rank] = lane*64 + bitpos;
        }
    }
    __syncthreads();

    for (int r = tid; r < POST_; r += 1024) {
        int i = kept_s[r];
        float o1 = 0.f, o2 = 0.f, o3 = 0.f, o4 = 0.f;
        if (i >= 0) { float4 bx = sbox[i]; o1 = bx.x; o2 = bx.y; o3 = bx.z; o4 = bx.w; }
        float* rowp = out0 + (u64)(b*POST_ + r)*5;
        rowp[0] = (float)b;
        rowp[1] = o1; rowp[2] = o2; rowp[3] = o3; rowp[4] = o4;
    }
}

extern "C" void kernel_launch(void* const* d_in, const int* in_sizes, int n_in,
                              void* d_out, int out_size, void* d_ws, size_t ws_size,
                              hipStream_t stream) {
    const float* scores  = (const float*)d_in[0];
    const float* deltas  = (const float*)d_in[1];
    const float* anchors = (const float*)d_in[2];
    const float* im_info = (const float*)d_in[3];
    const float* thrp    = (const float*)d_in[7];   // nms_thresh

    float* out0    = (float*)d_out;                 // (16, 300, 5)
    float* outprop = out0 + (u64)B_*POST_*5;        // (16, 147456, 4)

    char* ws = (char*)d_ws;
    u32*    state  = (u32*)   (ws + OFF_STATE);
    u32*    hist0  = (u32*)   (ws + OFF_HIST);
    u32*    hist1  = hist0 + B_*256;
    u32*    hist2  = hist1 + B_*256;
    u32*    hist3  = hist2 + B_*256;
    u32*    keys   = (u32*)   (ws + OFF_KEYS);
    u64*    cand   = (u64*)   (ws + OFF_CAND);
    float4* selbox = (float4*)(ws + OFF_SELBOX);
    u64*    livew  = (u64*)   (ws + OFF_LIVE);

    hipMemsetAsync(ws, 0, OFF_HIST + 4*B_*256*4, stream);

    decode_kernel<<<(B_*A_*HW_)/256, 256, 0, stream>>>(scores, deltas, anchors, im_info, outprop, keys, hist0);
    select_kernel<<<B_, 64, 0, stream>>>(hist0, state, 24);
    hist_kernel  <<<B_*16, 1024, 0, stream>>>(keys, state, hist1, 16);
    select_kernel<<<B_, 64, 0, stream>>>(hist1, state, 16);
    hist_kernel  <<<B_*16, 1024, 0, stream>>>(keys, state, hist2, 8);
    select_kernel<<<B_, 64, 0, stream>>>(hist2, state, 8);
    hist_kernel  <<<B_*16, 1024, 0, stream>>>(keys, state, hist3, 0);
    select_kernel<<<B_, 64, 0, stream>>>(hist3, state, 0);
    collect_kernel<<<B_*16, 1024, 0, stream>>>(keys, state, cand);
    sort_kernel<<<B_, 1024, 0, stream>>>(cand, state, outprop, selbox, livew);
    nms_fused_kernel<<<B_, 1024, 0, stream>>>(selbox, livew, thrp, out0);
}

// Round 3
// 415.488 us; speedup vs baseline: 1.8793x; 1.5412x over previous
//
#include <hip/hip_runtime.h>
#include <stdint.h>

#define B_ 16
#define A_ 9
#define H_ 128
#define W_ 128
#define HW_ (H_*W_)
#define N_ (HW_*A_)          // 147456 proposals per image
#define PRE_ 2000
#define POST_ 300
#define CAND_CAP 4096
#define CACHE_ROWS 512       // supp rows prefetched into LDS in scan

typedef unsigned int u32;
typedef unsigned long long u64;

// ---- workspace layout (bytes) ----
#define OFF_STATE  0ull                               // B * 8 u32 = 512
#define OFF_HIST   1024ull                            // 4 * B*256 u32 = 65536
#define OFF_KEYS   (OFF_HIST + 65536ull)
#define OFF_CAND   (OFF_KEYS + (u64)B_*N_*4)
#define OFF_SELBOX (OFF_CAND + (u64)B_*CAND_CAP*8)
#define OFF_LIVE   (OFF_SELBOX + (u64)B_*PRE_*16)
#define OFF_SUPP   (OFF_LIVE + (u64)B_*32*8)
// end = OFF_SUPP + B*PRE*32*8  (~18.7 MB total)

__device__ __forceinline__ u32 mono_key(float f) {
    u32 u = __float_as_uint(f);
    return (u & 0x80000000u) ? ~u : (u | 0x80000000u);
}

// ---------------- stage 1: decode boxes + fg scores + keys + pass-1 histogram ----------------
__global__ __launch_bounds__(256) void decode_kernel(
        const float* __restrict__ scores,
        const float* __restrict__ deltas,
        const float* __restrict__ anchors,
        const float* __restrict__ im_info,
        float* __restrict__ outprop,
        u32* __restrict__ keys,
        u32* __restrict__ hist0) {
    __shared__ float4 sbase[A_];
    __shared__ u32 h[256];
    int tid = threadIdx.x;
    if (tid < A_) sbase[tid] = ((const float4*)anchors)[tid];  // anchors[p=0] == base anchors
    h[tid] = 0;
    __syncthreads();

    int t = blockIdx.x * 256 + tid;
    int p  = t & (HW_ - 1);
    int ba = t >> 14;
    int a = ba % A_;
    int b = ba / A_;

    float s0 = scores[((b*2*A_ + a)      << 14) + p];
    float s1 = scores[((b*2*A_ + A_ + a) << 14) + p];
    float m  = fmaxf(s0, s1);
    float e0 = expf(s0 - m);
    float e1 = expf(s1 - m);
    float fg = e1 / (e0 + e1);

    float4 base = sbase[a];
    int ix = p & (W_-1), iy = p >> 7;
    float sx = (float)(ix * 16), sy = (float)(iy * 16);
    float ax1 = base.x + sx, ay1 = base.y + sy, ax2 = base.z + sx, ay2 = base.w + sy;

    float w  = ax2 - ax1 + 1.0f;
    float h_ = ay2 - ay1 + 1.0f;
    float cx = ax1 + 0.5f*w;
    float cy = ay1 + 0.5f*h_;

    const float* dbase = deltas + (u64)(((b*4*A_ + 4*a) << 14) + p);
    float dx = dbase[0];
    float dy = dbase[HW_];
    float dw = dbase[2*HW_];
    float dh = dbase[3*HW_];

    float pcx = dx*w  + cx;
    float pcy = dy*h_ + cy;
    float pw  = expf(dw)*w;
    float ph  = expf(dh)*h_;
    float x1 = pcx - 0.5f*pw, y1 = pcy - 0.5f*ph;
    float x2 = pcx + 0.5f*pw, y2 = pcy + 0.5f*ph;

    float wmax = im_info[b*4 + 1] - 1.0f;
    float hmax = im_info[b*4 + 0] - 1.0f;
    x1 = fminf(fmaxf(x1, 0.0f), wmax);
    y1 = fminf(fmaxf(y1, 0.0f), hmax);
    x2 = fminf(fmaxf(x2, 0.0f), wmax);
    y2 = fminf(fmaxf(y2, 0.0f), hmax);

    int n = p*A_ + a;
    ((float4*)outprop)[(u64)b*N_ + n] = make_float4(x1, y1, x2, y2);

    float bw = x2 - x1 + 1.0f;
    float bh = y2 - y1 + 1.0f;
    bool valid = (bw >= 16.0f*im_info[b*4 + 3]) && (bh >= 16.0f*im_info[b*4 + 2]);
    float sc = valid ? fg : -__builtin_inff();
    u32 k = mono_key(sc);
    keys[((u64)(b*A_ + a) << 14) + p] = k;       // coalesced (a,p) layout
    atomicAdd(&h[k >> 24], 1u);
    __syncthreads();
    if (h[tid]) atomicAdd(&hist0[b*256 + tid], h[tid]);
}

// ---------------- stage 2a: histogram pass (shifts 16, 8, 0), prefix-filtered ----------------
__global__ __launch_bounds__(1024) void hist_kernel(
        const u32* __restrict__ keys, const u32* __restrict__ state,
        u32* __restrict__ hist, int shift) {
    int b = blockIdx.x >> 4;
    int slice = blockIdx.x & 15;
    if (state[b*8 + 3]) return;                   // already done
    __shared__ u32 h[256];
    int tid = threadIdx.x;
    for (int i = tid; i < 256; i += 1024) h[i] = 0;
    __syncthreads();
    u32 prefix = state[b*8 + 0];
    const u32* kb = keys + (u64)b*N_ + slice*(N_/16);
    for (int n = tid; n < N_/16; n += 1024) {
        u32 k = kb[n];
        if ((k >> (shift + 8)) == prefix) atomicAdd(&h[(k >> shift) & 255u], 1u);
    }
    __syncthreads();
    for (int i = tid; i < 256; i += 1024)
        if (h[i]) atomicAdd(&hist[b*256 + i], h[i]);
}

// ---------------- stage 2b: pick bin (parallel suffix-scan over 256 bins) ----------------
__global__ __launch_bounds__(64) void select_kernel(
        const u32* __restrict__ hist, u32* __restrict__ state, int shift) {
    int b = blockIdx.x, lane = threadIdx.x;
    if (state[b*8 + 3]) return;
    u32 rem0   = (shift == 24) ? (u32)PRE_ : state[b*8 + 1];
    u32 prefix = (shift == 24) ? 0u        : state[b*8 + 0];
    uint4 hv = ((const uint4*)(hist + b*256))[lane];
    u32 psum = hv.x + hv.y + hv.z + hv.w;
    u32 s = psum;
    #pragma unroll
    for (int off = 1; off < 64; off <<= 1) {
        u32 o = (u32)__shfl_down((int)s, off);
        if (lane + off < 64) s += o;
    }
    u32 S_next = (u32)__shfl_down((int)s, 1);
    if (lane == 63) S_next = 0;
    u32 above[4], cnt[4];
    above[3] = S_next;             cnt[3] = hv.w;
    above[2] = S_next + hv.w;      cnt[2] = hv.z;
    above[1] = above[2] + hv.z;    cnt[1] = hv.y;
    above[0] = above[1] + hv.y;    cnt[0] = hv.x;
    #pragma unroll
    for (int j = 3; j >= 0; --j) {
        if (above[j] < rem0 && above[j] + cnt[j] >= rem0) {
            u32 bin = (u32)(4*lane + j);
            u32 newpref = (prefix << 8) | bin;
            u32 rem = rem0 - above[j];
            u32 candTotal = ((u32)PRE_ - rem) + cnt[j];
            if (candTotal <= (u32)CAND_CAP || shift == 0) {
                state[b*8 + 4] = newpref << shift;     // threshold key T
                state[b*8 + 3] = 1;                    // done
            } else {
                state[b*8 + 0] = newpref;
                state[b*8 + 1] = rem;
            }
        }
    }
}

// ---------------- stage 3: collect all keys >= T ----------------
__global__ __launch_bounds__(1024) void collect_kernel(
        const u32* __restrict__ keys, u32* __restrict__ state, u64* __restrict__ cand) {
    int b = blockIdx.x >> 4;
    int slice = blockIdx.x & 15;
    u32 T = state[b*8 + 4];
    const u32* kb = keys + (u64)b*N_ + slice*(N_/16);
    u64* cb = cand + (u64)b*CAND_CAP;
    int tid = threadIdx.x;
    for (int i = tid; i < N_/16; i += 1024) {
        u32 k = kb[i];
        if (k >= T) {
            u32 pos = atomicAdd((u32*)&state[b*8 + 2], 1u);
            int idx = slice*(N_/16) + i;
            u32 n = (u32)((idx & (HW_-1))*A_ + (idx >> 14));  // n = p*9 + a
            if (pos < CAND_CAP) cb[pos] = ((u64)k << 32) | (u32)(~n);
        }
    }
}

// ---------------- stage 4: bitonic sort candidates, gather top-2000 boxes ----------------
__global__ __launch_bounds__(1024) void sort_kernel(
        const u64* __restrict__ cand, const u32* __restrict__ state,
        const float* __restrict__ outprop,
        float4* __restrict__ selbox, u64* __restrict__ livew) {
    int b = blockIdx.x, tid = threadIdx.x;
    __shared__ u64 s[CAND_CAP];
    __shared__ unsigned char lv[2048];
    u32 cnt = state[b*8 + 2];
    if (cnt > CAND_CAP) cnt = CAND_CAP;
    const u64* cb = cand + (u64)b*CAND_CAP;
    for (int i = tid; i < CAND_CAP; i += 1024) s[i] = (i < (int)cnt) ? cb[i] : 0ull;
    for (int i = tid; i < 2048; i += 1024) lv[i] = 0;

    for (u32 k = 2; k <= CAND_CAP; k <<= 1) {
        for (u32 j = k >> 1; j > 0; j >>= 1) {
            __syncthreads();
            for (u32 e = tid; e < CAND_CAP; e += 1024) {
                u32 ixj = e ^ j;
                if (ixj > e) {
                    u64 x = s[e], y = s[ixj];
                    bool descend = ((e & k) == 0);
                    if (descend ? (x < y) : (x > y)) { s[e] = y; s[ixj] = x; }
                }
            }
        }
    }
    __syncthreads();
    for (int r = tid; r < PRE_; r += 1024) {
        u64 e = s[r];
        u32 key = (u32)(e >> 32);
        u32 n = ~(u32)e;
        float4 box = make_float4(0.f, 0.f, 0.f, 0.f);
        if (e != 0ull) box = ((const float4*)outprop)[(u64)b*N_ + n];
        selbox[(u64)b*PRE_ + r] = box;
        lv[r] = (key >= 0x80000000u) ? 1 : 0;   // finite (valid) score
    }
    __syncthreads();
    for (int w = tid; w < 32; w += 1024) {
        u64 word = 0;
        for (int bit = 0; bit < 64; ++bit) {
            int r = w*64 + bit;
            if (r < PRE_ && lv[r]) word |= (1ull << bit);
        }
        livew[b*32 + w] = word;
    }
}

// ---------------- stage 5: 2000x2000 IoU suppression bitmask (full-device parallel) ----------------
__global__ __launch_bounds__(256) void iou_kernel(
        const float4* __restrict__ selbox, const float* __restrict__ thrp,
        u64* __restrict__ supp) {
    int bi = blockIdx.x;             // B * 250 blocks, 8 rows each
    int b = bi / 250;
    int rbase = (bi % 250) * 8;
    int tid = threadIdx.x;
    __shared__ float4 box[PRE_];
    for (int i = tid; i < PRE_; i += 256) box[i] = selbox[(u64)b*PRE_ + i];
    __syncthreads();
    float thresh = thrp[0];
    int wv = tid >> 6, lane = tid & 63;

    float4 p[8]; float ai[8];
    #pragma unroll
    for (int r = 0; r < 8; ++r) {
        p[r]  = box[rbase + r];
        ai[r] = (p[r].z - p[r].x + 1.f) * (p[r].w - p[r].y + 1.f);
    }
    for (int c = 0; c < 8; ++c) {
        int j = c*256 + tid;
        bool inb = (j < PRE_);
        float4 q = box[inb ? j : 0];
        float aj = (q.z - q.x + 1.f) * (q.w - q.y + 1.f);
        #pragma unroll
        for (int r = 0; r < 8; ++r) {
            float iw = fminf(p[r].z, q.z) - fmaxf(p[r].x, q.x) + 1.f;
            float ih = fminf(p[r].w, q.w) - fmaxf(p[r].y, q.y) + 1.f;
            iw = fmaxf(iw, 0.f); ih = fmaxf(ih, 0.f);
            float inter = iw * ih;
            bool pred = inb && ((inter / (ai[r] + aj - inter)) > thresh);
            u64 ball = __ballot(pred);
            if (lane == 0)
                supp[((u64)(b*PRE_ + rbase + r))*32 + (c*4 + wv)] = ball;
        }
    }
}

// ---------------- stage 6: greedy scan, kept-rows-only chain + LDS row cache + output ----------------
__global__ __launch_bounds__(1024) void scan_kernel(
        const u64* __restrict__ supp, const u64* __restrict__ livew,
        const float4* __restrict__ selbox, float* __restrict__ out0) {
    int b = blockIdx.x;
    int tid = threadIdx.x;
    int wave = tid >> 6, lane = tid & 63;

    __shared__ u64 rows[CACHE_ROWS][32];     // 131072 B
    __shared__ int rowof[CACHE_ROWS];
    __shared__ int pref[32];                 // exclusive prefix popcounts of live words
    __shared__ u64 ow[32];                   // original live words
    __shared__ int kept[POST_];
    __shared__ int s_kc, s_nlive;

    // wave 0: build live-rank structures
    if (wave == 0) {
        u64 w = (lane < 32) ? livew[b*32 + lane] : 0ull;
        if (lane < 32) ow[lane] = w;
        int pc = (int)__builtin_popcountll(w);
        int x = pc;
        #pragma unroll
        for (int off = 1; off < 64; off <<= 1) {
            int y = __shfl_up(x, off);
            if (lane >= off) x += y;
        }
        int excl = x - pc;
        if (lane < 32) pref[lane] = excl;
        if (lane == 31) s_nlive = x;
        // enumerate set bits -> rowof[slot]
        int c = 0;
        u64 t = w;
        while (t) {
            int bit = (int)__builtin_ctzll(t);
            t &= t - 1;
            int slot = excl + c; c++;
            if (slot < CACHE_ROWS) rowof[slot] = lane*64 + bit;
        }
    }
    __syncthreads();

    int nslot = s_nlive < CACHE_ROWS ? s_nlive : CACHE_ROWS;
    // all 16 waves: prefetch supp rows of the first nslot live rows into LDS
    for (int s = wave; s < nslot; s += 16) {
        int r = rowof[s];
        if (lane < 32) rows[s][lane] = supp[((u64)(b*PRE_ + r))*32 + lane];
    }
    if (tid == 0) s_kc = 0;
    __syncthreads();

    if (wave == 0) {
        u64 alive = (lane < 32) ? ow[lane] : 0ull;
        int kc = 0;
        int cur = -1;
        // helper expressed inline: find next alive bit > cur
        for (;;) {
            int wi = cur >> 6;                   // -1 -> all lanes pass
            int bit = cur & 63;
            u64 gt;
            if (lane > wi)       gt = ~0ull;
            else if (lane == wi) gt = (bit == 63) ? 0ull : (~0ull << (bit + 1));
            else                 gt = 0ull;
            u64 m = alive & gt;
            u64 bal = __ballot(m != 0ull);
            if (bal == 0ull || kc >= POST_) break;
            int w2 = (int)__builtin_ctzll(bal);
            u32 lo = (u32)__shfl((int)(u32)(m & 0xFFFFFFFFull), w2);
            u32 hi = (u32)__shfl((int)(u32)(m >> 32), w2);
            u64 word = ((u64)hi << 32) | lo;
            int nxt = w2*64 + (int)__builtin_ctzll(word);

            // keep nxt; suppress with its row
            kept[kc++] = nxt;
            int nwi = nxt >> 6, nbit = nxt & 63;
            // live-rank of nxt for LDS cache lookup
            int rk = pref[nwi] + (int)__builtin_popcountll(ow[nwi] & ((nbit == 0) ? 0ull : (~0ull >> (64 - nbit))));
            u64 rv;
            if (rk < nslot) rv = (lane < 32) ? rows[rk][lane] : 0ull;
            else            rv = (lane < 32) ? supp[((u64)(b*PRE_ + nxt))*32 + lane] : 0ull;
            // mask j > nxt
            u64 gt2;
            if (lane > nwi)       gt2 = ~0ull;
            else if (lane == nwi) gt2 = (nbit == 63) ? 0ull : (~0ull << (nbit + 1));
            else                  gt2 = 0ull;
            alive &= ~(rv & gt2);
            cur = nxt;
        }
        if (lane == 0) s_kc = kc;
    }
    __syncthreads();

    int kc = s_kc;
    for (int r = tid; r < POST_; r += 1024) {
        int i = (r < kc) ? kept[r] : -1;
        float o1 = 0.f, o2 = 0.f, o3 = 0.f, o4 = 0.f;
        if (i >= 0) {
            float4 bx = selbox[(u64)b*PRE_ + i];
            o1 = bx.x; o2 = bx.y; o3 = bx.z; o4 = bx.w;
        }
        float* rowp = out0 + (u64)(b*POST_ + r)*5;
        rowp[0] = (float)b;
        rowp[1] = o1; rowp[2] = o2; rowp[3] = o3; rowp[4] = o4;
    }
}

extern "C" void kernel_launch(void* const* d_in, const int* in_sizes, int n_in,
                              void* d_out, int out_size, void* d_ws, size_t ws_size,
                              hipStream_t stream) {
    const float* scores  = (const float*)d_in[0];
    const float* deltas  = (const float*)d_in[1];
    const float* anchors = (const float*)d_in[2];
    const float* im_info = (const float*)d_in[3];
    const float* thrp    = (const float*)d_in[7];   // nms_thresh

    float* out0    = (float*)d_out;                 // (16, 300, 5)
    float* outprop = out0 + (u64)B_*POST_*5;        // (16, 147456, 4)

    char* ws = (char*)d_ws;
    u32*    state  = (u32*)   (ws + OFF_STATE);
    u32*    hist0  = (u32*)   (ws + OFF_HIST);
    u32*    hist1  = hist0 + B_*256;
    u32*    hist2  = hist1 + B_*256;
    u32*    hist3  = hist2 + B_*256;
    u32*    keys   = (u32*)   (ws + OFF_KEYS);
    u64*    cand   = (u64*)   (ws + OFF_CAND);
    float4* selbox = (float4*)(ws + OFF_SELBOX);
    u64*    livew  = (u64*)   (ws + OFF_LIVE);
    u64*    supp   = (u64*)   (ws + OFF_SUPP);

    hipMemsetAsync(ws, 0, OFF_HIST + 4*B_*256*4, stream);

    decode_kernel<<<(B_*A_*HW_)/256, 256, 0, stream>>>(scores, deltas, anchors, im_info, outprop, keys, hist0);
    select_kernel<<<B_, 64, 0, stream>>>(hist0, state, 24);
    hist_kernel  <<<B_*16, 1024, 0, stream>>>(keys, state, hist1, 16);
    select_kernel<<<B_, 64, 0, stream>>>(hist1, state, 16);
    hist_kernel  <<<B_*16, 1024, 0, stream>>>(keys, state, hist2, 8);
    select_kernel<<<B_, 64, 0, stream>>>(hist2, state, 8);
    hist_kernel  <<<B_*16, 1024, 0, stream>>>(keys, state, hist3, 0);
    select_kernel<<<B_, 64, 0, stream>>>(hist3, state, 0);
    collect_kernel<<<B_*16, 1024, 0, stream>>>(keys, state, cand);
    sort_kernel<<<B_, 1024, 0, stream>>>(cand, state, outprop, selbox, livew);
    iou_kernel<<<B_*250, 256, 0, stream>>>(selbox, thrp, supp);
    scan_kernel<<<B_, 1024, 0, stream>>>(supp, livew, selbox, out0);
}